// Round 10
// baseline (129.651 us; speedup 1.0000x reference)
//
#include <hip/hip_runtime.h>
#include <math.h>

#define HW 16384
#define Wd 128

typedef __attribute__((ext_vector_type(8))) short short8;
typedef __attribute__((ext_vector_type(4))) float f32x4;

__device__ __forceinline__ unsigned cvt_pk_bf16(float a, float b) {
  unsigned r;                                   // r = bf16(a) | bf16(b)<<16
  asm("v_cvt_pk_bf16_f32 %0, %1, %2" : "=v"(r) : "v"(a), "v"(b));
  return r;
}

__device__ __forceinline__ unsigned short bf16r(float f) {
  unsigned int u = __float_as_uint(f);
  unsigned int r = (u + 0x7FFFu + ((u >> 16) & 1u)) >> 16;   // RNE
  return (unsigned short)r;
}

// ---------------- K1: per (b,c) spatial mean ----------------
__global__ void k_mean(const float* __restrict__ x, float* __restrict__ xmean) {
  int bc = blockIdx.x;                       // 0..95  (b*48+c)
  const float* p = x + (size_t)bc * HW;
  float s = 0.f;
  for (int i = threadIdx.x; i < HW; i += 256) s += p[i];
  #pragma unroll
  for (int off = 32; off > 0; off >>= 1) s += __shfl_down(s, off, 64);
  __shared__ float wsum[4];
  int lane = threadIdx.x & 63, wv = threadIdx.x >> 6;
  if (lane == 0) wsum[wv] = s;
  __syncthreads();
  if (threadIdx.x == 0)
    xmean[bc] = (wsum[0] + wsum[1] + wsum[2] + wsum[3]) * (1.f / 16384.f);
}

__global__ void k_sca(const float* __restrict__ xmean, const float* __restrict__ w_sca,
                      const float* __restrict__ b_sca, float* __restrict__ sca) {
  int t = threadIdx.x;
  if (t < 192) {
    int b = t / 96, co = t % 96;
    float acc = b_sca[co];
    for (int ci = 0; ci < 48; ci++) acc += w_sca[co * 48 + ci] * xmean[b * 48 + ci];
    sca[t] = acc;
  }
}

// ---------------- K3: two 1x1 convs 48->96, 2 px/thread ----------------
// grid (256,4): 128 px per block; slot handles 6 out-channels
__global__ void k_pw1(const float* __restrict__ x,
                      const float* __restrict__ w1a, const float* __restrict__ b1a,
                      const float* __restrict__ w1c, const float* __restrict__ b1c,
                      float* __restrict__ ha, float* __restrict__ hc) {
  int lane = threadIdx.x & 63;
  int wv = __builtin_amdgcn_readfirstlane((int)(threadIdx.x >> 6));
  int slot = __builtin_amdgcn_readfirstlane((int)(blockIdx.y * 4 + wv));
  int p2 = blockIdx.x * 128 + lane * 2;
  int b = p2 >> 14, sp = p2 & (HW - 1);
  const float* xb = x + (size_t)b * 48 * HW + sp;
  float2 xv[48];
  #pragma unroll
  for (int ci = 0; ci < 48; ci++) xv[ci] = *(const float2*)(xb + (size_t)ci * HW);
  float* hab = ha + (size_t)b * 96 * HW + sp;
  float* hcb = hc + (size_t)b * 96 * HW + sp;
  int c0 = slot * 6;
  for (int co = c0; co < c0 + 6; co++) {
    float ax = b1a[co], ay = ax, cx = b1c[co], cy = cx;
    const float* wa = w1a + co * 48;
    const float* wc = w1c + co * 48;
    #pragma unroll
    for (int ci = 0; ci < 48; ci++) {
      float w0 = wa[ci], w1 = wc[ci];
      ax += w0 * xv[ci].x; ay += w0 * xv[ci].y;
      cx += w1 * xv[ci].x; cy += w1 * xv[ci].y;
    }
    *(float2*)(hab + (size_t)co * HW) = make_float2(ax, ay);
    *(float2*)(hcb + (size_t)co * HW) = make_float2(cx, cy);
  }
}

// ---------------- K4: depthwise 3x3, 2 px/thread; gelu*sca folded into x1 path ----
__global__ void k_dw(const float* __restrict__ ha, const float* __restrict__ hc,
                     const float* __restrict__ wdwa, const float* __restrict__ bdwa,
                     const float* __restrict__ wdwc, const float* __restrict__ bdwc,
                     const float* __restrict__ sca,
                     float* __restrict__ x1g, float* __restrict__ uf) {
  int idx = blockIdx.x * 256 + threadIdx.x;        // < B*96*HW/2 = 1572864
  int sp2 = idx & 8191;
  int bc = idx >> 13;                              // b*96+ch
  int ch = bc % 96;
  int sp = sp2 * 2;
  int r = sp >> 7, c = sp & 127;                   // c even
  const float* pa = ha + (size_t)bc * HW;
  const float* pc = hc + (size_t)bc * HW;
  bool cm = (c > 0), cp = (c < 126);
  float ax = bdwa[ch], ay = ax, gx = bdwc[ch], gy = gx;
  #pragma unroll
  for (int ri = 0; ri < 3; ri++) {
    int rr = r + ri - 1;
    bool okr = ((unsigned)rr < 128u);
    const float* ra = pa + rr * Wd;
    const float* rc = pc + rr * Wd;
    float a0 = (okr && cm) ? ra[c - 1] : 0.f;
    float a1 = okr ? ra[c] : 0.f;
    float a2 = okr ? ra[c + 1] : 0.f;
    float a3 = (okr && cp) ? ra[c + 2] : 0.f;
    float c_0 = (okr && cm) ? rc[c - 1] : 0.f;
    float c_1 = okr ? rc[c] : 0.f;
    float c_2 = okr ? rc[c + 1] : 0.f;
    float c_3 = (okr && cp) ? rc[c + 2] : 0.f;
    float wa0 = wdwa[ch * 9 + ri * 3], wa1 = wdwa[ch * 9 + ri * 3 + 1], wa2 = wdwa[ch * 9 + ri * 3 + 2];
    float wc0 = wdwc[ch * 9 + ri * 3], wc1 = wdwc[ch * 9 + ri * 3 + 1], wc2 = wdwc[ch * 9 + ri * 3 + 2];
    ax += wa0 * a0 + wa1 * a1 + wa2 * a2;
    ay += wa0 * a1 + wa1 * a2 + wa2 * a3;
    gx += wc0 * c_0 + wc1 * c_1 + wc2 * c_2;
    gy += wc0 * c_1 + wc1 * c_2 + wc2 * c_3;
  }
  float sc = sca[bc];
  float glx = ax * 0.5f * (1.f + erff(ax * 0.70710678118654752440f)) * sc;
  float gly = ay * 0.5f * (1.f + erff(ay * 0.70710678118654752440f)) * sc;
  *(float2*)(x1g + (size_t)bc * HW + sp) = make_float2(glx, gly);
  *(float2*)(uf + (size_t)bc * HW + sp) = make_float2(gx, gy);
}

// ---------------- K5a: gate m = t1*t2, 2 px/thread ----------------
__global__ void k_gate(const float* __restrict__ x, const float* __restrict__ wc2a,
                       const float* __restrict__ bc2a, float* __restrict__ m) {
  int idx = blockIdx.x * 256 + threadIdx.x;        // < B*12*HW/2 = 196608
  int sp2 = idx & 8191;
  int bi = idx >> 13;                              // b*12+i
  int i = bi % 12, b = bi / 12;
  int sp = sp2 * 2;
  int r = sp >> 7, c = sp & 127;
  bool cm = (c > 0), cp = (c < 126);
  const float* xb = x + (size_t)b * 48 * HW;
  float tx[2], ty[2];
  #pragma unroll
  for (int half = 0; half < 2; half++) {
    int o = i + half * 12;
    float accx = bc2a[o], accy = accx;
    #pragma unroll
    for (int ic = 0; ic < 2; ic++) {
      const float* xc = xb + (size_t)(2 * o + ic) * HW;
      const float* wo = wc2a + o * 18 + ic * 9;
      #pragma unroll
      for (int ri = 0; ri < 3; ri++) {
        int rr = r + ri - 1;
        bool okr = ((unsigned)rr < 128u);
        const float* rowp = xc + rr * Wd;
        float v0 = (okr && cm) ? rowp[c - 1] : 0.f;
        float v1 = okr ? rowp[c] : 0.f;
        float v2 = okr ? rowp[c + 1] : 0.f;
        float v3 = (okr && cp) ? rowp[c + 2] : 0.f;
        float w0 = wo[ri * 3], w1 = wo[ri * 3 + 1], w2 = wo[ri * 3 + 2];
        accx += w0 * v0 + w1 * v1 + w2 * v2;
        accy += w0 * v1 + w1 * v2 + w2 * v3;
      }
    }
    tx[half] = accx; ty[half] = accy;
  }
  *(float2*)(m + (size_t)bi * HW + sp) = make_float2(tx[0] * tx[1], ty[0] * ty[1]);
}

// ---------------- K5b: att = 1x1(m)*gamma + 1x1(x), 2 px/thread ----------------
// grid (256,4): slot (0..15) handles 2 att channels
__global__ void k_att2(const float* __restrict__ x, const float* __restrict__ m,
                       const float* __restrict__ wc2b, const float* __restrict__ bc2b,
                       const float* __restrict__ w211, const float* __restrict__ b211,
                       const float* __restrict__ attg, float* __restrict__ att) {
  int lane = threadIdx.x & 63;
  int wv = __builtin_amdgcn_readfirstlane((int)(threadIdx.x >> 6));
  int slot = __builtin_amdgcn_readfirstlane((int)(blockIdx.y * 4 + wv));
  int p2 = blockIdx.x * 128 + lane * 2;
  int b = p2 >> 14, sp = p2 & (HW - 1);
  float2 mv[12];
  const float* mb = m + (size_t)b * 12 * HW + sp;
  #pragma unroll
  for (int i = 0; i < 12; i++) mv[i] = *(const float2*)(mb + (size_t)i * HW);
  float2 xv[48];
  const float* xb = x + (size_t)b * 48 * HW + sp;
  #pragma unroll
  for (int ci = 0; ci < 48; ci++) xv[ci] = *(const float2*)(xb + (size_t)ci * HW);
  float* ab = att + (size_t)b * 32 * HW + sp;
  int n0 = slot * 2;
  for (int n = n0; n < n0 + 2; n++) {
    float a1x = bc2b[n], a1y = a1x;
    #pragma unroll
    for (int i = 0; i < 12; i++) {
      float w = wc2b[n * 12 + i];
      a1x += w * mv[i].x; a1y += w * mv[i].y;
    }
    float a2x = b211[n], a2y = a2x;
    #pragma unroll
    for (int ci = 0; ci < 48; ci++) {
      float w = w211[n * 48 + ci];
      a2x += w * xv[ci].x; a2y += w * xv[ci].y;
    }
    float gmm = attg[n];
    *(float2*)(ab + (size_t)n * HW) = make_float2(a1x * gmm + a2x, a1y * gmm + a2y);
  }
}

// ---------------- K_prep: repack kbw+kbb -> bf16 A-tile [48][64][32] ----------------
// K-slot map (center-aligned; q = k>>3, j2 = k&7):
//   q0: j2<5 -> jj = j2        (ch0 taps 0-4; center jj=4 at j2=4)
//   q1: j2<5 -> jj = 9+j2      (ch1 taps 0-4; center jj=13 at j2=4)
//   q2: j2<4 -> jj = 5+j2      (ch0 taps 5-8)
//   q3: j2<4 -> jj = 14+j2     (ch1 taps 5-8); j2==4 -> bias
__global__ void k_prep(const float* __restrict__ kbw, const float* __restrict__ kbb,
                       unsigned short* __restrict__ kwA) {
  int e = blockIdx.x * 256 + threadIdx.x;          // < 48*64*32 = 98304
  int k = e & 31, nc = (e >> 5) & 63, g = e >> 11;
  int n = nc >> 1, i = nc & 1;
  int q = k >> 3, j2 = k & 7;
  float v = 0.f;
  int jj = -1;
  if (q == 0)      { if (j2 < 5) jj = j2; }
  else if (q == 1) { if (j2 < 5) jj = 9 + j2; }
  else if (q == 2) { if (j2 < 4) jj = 5 + j2; }
  else             { if (j2 < 4) jj = 14 + j2; else if (j2 == 4) v = kbb[n * 96 + 2 * g + i]; }
  if (jj >= 0) v = kbw[n * 1728 + g * 36 + i * 18 + jj];
  kwA[e] = bf16r(v);
}

// ---------------- K6: fused kba via MFMA, LDS kwA + full tap prefetch ----------
// grid (512,6) x 256. Wave wv owns px [wv*16,+16); block covers 8 groups gq*8..+7.
// ALL 40 tap loads issued in one preamble block (leave the loop's critical path
// pure LDS+MFMA+VALU); kwA staged in LDS (32 KB).
// Output y2: packed bf16 channel-pairs [B][48][HW] (u32 = ch_even | ch_odd<<16).
__global__ __launch_bounds__(256) void k_kba(
    const float* __restrict__ uf, const float* __restrict__ x1g,
    const float* __restrict__ att, const unsigned short* __restrict__ kwA,
    const float* __restrict__ ga1, unsigned int* __restrict__ y2) {
  __shared__ __align__(16) short kwS[8 * 2048];    // 32 KB
  int tid = threadIdx.x;
  int lane = tid & 63;
  int wv = tid >> 6;
  int lo = lane & 15, hi = lane >> 4;
  int bid = blockIdx.x;                            // 0..511
  int b = bid >> 8;
  int sp = ((bid & 255) << 6) + wv * 16 + lo;      // this lane's pixel
  int r = sp >> 7, c = sp & 127;
  int g0 = blockIdx.y * 8;

  // stage this block's 8 groups of kwA into LDS (coalesced 16B copies)
  {
    const short8* src = (const short8*)(kwA + g0 * 2048);
    short8* dst = (short8*)kwS;
    #pragma unroll
    for (int i = 0; i < 8; i++) dst[tid + 256 * i] = src[tid + 256 * i];
  }

  const float* ufb  = uf  + (size_t)b * 96 * HW;
  const float* x1gb = x1g + (size_t)b * 96 * HW;
  const float* attb = att + (size_t)b * 32 * HW;
  unsigned int* y2b = y2 + (size_t)b * 48 * HW;

  // att[n][sp] for this lane's 8 n-slots: n = 8*mt + 2*hi + q
  float attv[8];
  #pragma unroll
  for (int mt = 0; mt < 4; mt++)
    #pragma unroll
    for (int q = 0; q < 2; q++)
      attv[mt * 2 + q] = attb[(size_t)(8 * mt + 2 * hi + q) * HW + sp];

  // tap descriptors for this lane's 5 K-slots (must match k_prep exactly;
  // the shared (hi,j2)->jj permutation cancels inside the MFMA)
  const float* pj[5];
  bool ok[5];
  float dv[5];
  #pragma unroll
  for (int j2 = 0; j2 < 5; j2++) {
    int jj = (hi == 0) ? j2 : (hi == 1) ? 9 + j2 : (hi == 2) ? 5 + j2 : 14 + j2;
    bool real = (hi < 2) || (j2 < 4);
    if (real) {
      int ch = jj / 9, tap = jj % 9;
      int rr = r + tap / 3 - 1, cc = c + tap % 3 - 1;
      bool inb = ((unsigned)rr < 128u) && ((unsigned)cc < 128u);
      ok[j2] = inb;
      dv[j2] = 0.f;
      pj[j2] = ufb + (size_t)(2 * g0 + ch) * HW + (inb ? rr * Wd + cc : 0);
    } else {
      ok[j2] = false;
      dv[j2] = (hi == 3) ? 1.f : 0.f;              // bias slot (q3, j2==4)
      pj[j2] = ufb;
    }
  }

  // prefetch ALL 8 groups' taps (40 loads in flight; compile-time offsets)
  float vT[8][5];
  #pragma unroll
  for (int gi = 0; gi < 8; gi++)
    #pragma unroll
    for (int j2 = 0; j2 < 5; j2++)
      vT[gi][j2] = ok[j2] ? pj[j2][(size_t)(2 * gi) * HW] : dv[j2];

  __syncthreads();                                 // staging complete

  #pragma unroll
  for (int gp = 0; gp < 4; gp++) {
    int g = g0 + 2 * gp;
    float* va = vT[2 * gp];
    float* vb = vT[2 * gp + 1];
    // A-frags from LDS (conflict-free: lane byte addr = lo*64 + hi*16)
    const short* kgA = kwS + (2 * gp) * 2048;
    const short* kgB = kgA + 2048;
    short8 afrA[4], afrB[4];
    #pragma unroll
    for (int mt = 0; mt < 4; mt++) {
      afrA[mt] = *(const short8*)(kgA + (16 * mt + lo) * 32 + hi * 8);
      afrB[mt] = *(const short8*)(kgB + (16 * mt + lo) * 32 + hi * 8);
    }
    union { unsigned u[4]; short8 s; } bfA, bfB;
    bfA.u[0] = cvt_pk_bf16(va[0], va[1]);
    bfA.u[1] = cvt_pk_bf16(va[2], va[3]);
    bfA.u[2] = cvt_pk_bf16(va[4], 0.f);
    bfA.u[3] = 0u;
    bfB.u[0] = cvt_pk_bf16(vb[0], vb[1]);
    bfB.u[1] = cvt_pk_bf16(vb[2], vb[3]);
    bfB.u[2] = cvt_pk_bf16(vb[4], 0.f);
    bfB.u[3] = 0u;
    f32x4 accA[4], accB[4];
    f32x4 zero = {0.f, 0.f, 0.f, 0.f};
    #pragma unroll
    for (int mt = 0; mt < 4; mt++)
      accA[mt] = __builtin_amdgcn_mfma_f32_16x16x32_bf16(afrA[mt], bfA.s, zero, 0, 0, 0);
    #pragma unroll
    for (int mt = 0; mt < 4; mt++)
      accB[mt] = __builtin_amdgcn_mfma_f32_16x16x32_bf16(afrB[mt], bfB.s, zero, 0, 0, 0);
    // --- reduce over n (group A overlaps group B's MFMA latency) ---
    float sA0 = 0.f, sA1 = 0.f, sB0 = 0.f, sB1 = 0.f;
    #pragma unroll
    for (int mt = 0; mt < 4; mt++) {
      sA0 += attv[mt * 2 + 0] * accA[mt][0] + attv[mt * 2 + 1] * accA[mt][2];
      sA1 += attv[mt * 2 + 0] * accA[mt][1] + attv[mt * 2 + 1] * accA[mt][3];
    }
    sA0 += __shfl_xor(sA0, 16); sA0 += __shfl_xor(sA0, 32);
    sA1 += __shfl_xor(sA1, 16); sA1 += __shfl_xor(sA1, 32);
    float cenA = __shfl_xor(va[4], 16);
    #pragma unroll
    for (int mt = 0; mt < 4; mt++) {
      sB0 += attv[mt * 2 + 0] * accB[mt][0] + attv[mt * 2 + 1] * accB[mt][2];
      sB1 += attv[mt * 2 + 0] * accB[mt][1] + attv[mt * 2 + 1] * accB[mt][3];
    }
    sB0 += __shfl_xor(sB0, 16); sB0 += __shfl_xor(sB0, 32);
    sB1 += __shfl_xor(sB1, 16); sB1 += __shfl_xor(sB1, 32);
    float cenB = __shfl_xor(vb[4], 16);
    // --- epilogue: quarter 0 packs & stores both channels of both groups ---
    if (hi == 0) {
      int c0 = 2 * g;
      float xa0 = sA0 * ga1[c0]     + va[4];
      float xa1 = sA1 * ga1[c0 + 1] + cenA;
      float ya0 = x1gb[(size_t)c0 * HW + sp] * xa0;
      float ya1 = x1gb[(size_t)(c0 + 1) * HW + sp] * xa1;
      y2b[(size_t)g * HW + sp] = cvt_pk_bf16(ya0, ya1);
      float xb0 = sB0 * ga1[c0 + 2] + vb[4];
      float xb1 = sB1 * ga1[c0 + 3] + cenB;
      float yb0 = x1gb[(size_t)(c0 + 2) * HW + sp] * xb0;
      float yb1 = x1gb[(size_t)(c0 + 3) * HW + sp] * xb1;
      y2b[(size_t)(g + 1) * HW + sp] = cvt_pk_bf16(yb0, yb1);
    }
  }
}

// ---------------- K7: project_out 96->48 from packed bf16 y2, 2 px/thread -------
// grid (256,4): slot (0..15) handles 3 out-channels; streaming accumulate
__global__ void k_proj(const unsigned int* __restrict__ y2, const float* __restrict__ wproj,
                       const float* __restrict__ bproj, float* __restrict__ out) {
  int lane = threadIdx.x & 63;
  int wv = __builtin_amdgcn_readfirstlane((int)(threadIdx.x >> 6));
  int slot = __builtin_amdgcn_readfirstlane((int)(blockIdx.y * 4 + wv));
  int p2 = blockIdx.x * 128 + lane * 2;
  int b = p2 >> 14, sp = p2 & (HW - 1);
  const unsigned int* yb = y2 + (size_t)b * 48 * HW + sp;
  int co0 = slot * 3;
  float2 acc[3];
  #pragma unroll
  for (int k = 0; k < 3; k++) acc[k] = make_float2(bproj[co0 + k], bproj[co0 + k]);
  #pragma unroll
  for (int g = 0; g < 48; g++) {
    uint2 u = *(const uint2*)(yb + (size_t)g * HW);
    float e0 = __uint_as_float(u.x << 16);          // ch 2g,   px sp
    float o0 = __uint_as_float(u.x & 0xffff0000u);  // ch 2g+1, px sp
    float e1 = __uint_as_float(u.y << 16);          // ch 2g,   px sp+1
    float o1 = __uint_as_float(u.y & 0xffff0000u);  // ch 2g+1, px sp+1
    #pragma unroll
    for (int k = 0; k < 3; k++) {
      float we = wproj[(co0 + k) * 96 + 2 * g];
      float wo = wproj[(co0 + k) * 96 + 2 * g + 1];
      acc[k].x += we * e0 + wo * o0;
      acc[k].y += we * e1 + wo * o1;
    }
  }
  float* ob = out + (size_t)b * 48 * HW + sp;
  #pragma unroll
  for (int k = 0; k < 3; k++)
    *(float2*)(ob + (size_t)(co0 + k) * HW) = acc[k];
}

extern "C" void kernel_launch(void* const* d_in, const int* in_sizes, int n_in,
                              void* d_out, int out_size, void* d_ws, size_t ws_size,
                              hipStream_t stream) {
  const float* x    = (const float*)d_in[0];
  const float* w1a  = (const float*)d_in[1];
  const float* b1a  = (const float*)d_in[2];
  const float* wdwa = (const float*)d_in[3];
  const float* bdwa = (const float*)d_in[4];
  const float* w1c  = (const float*)d_in[5];
  const float* b1c  = (const float*)d_in[6];
  const float* wdwc = (const float*)d_in[7];
  const float* bdwc = (const float*)d_in[8];
  const float* wsca = (const float*)d_in[9];
  const float* bsca = (const float*)d_in[10];
  const float* wc2a = (const float*)d_in[11];
  const float* bc2a = (const float*)d_in[12];
  const float* wc2b = (const float*)d_in[13];
  const float* bc2b = (const float*)d_in[14];
  const float* w211 = (const float*)d_in[15];
  const float* b211 = (const float*)d_in[16];
  const float* wproj= (const float*)d_in[17];
  const float* bproj= (const float*)d_in[18];
  const float* kbw  = (const float*)d_in[19];
  const float* kbb  = (const float*)d_in[20];
  const float* attg = (const float*)d_in[21];
  const float* ga1  = (const float*)d_in[22];
  float* out = (float*)d_out;

  float* ws    = (float*)d_ws;
  float* xmean = ws;                 // 96
  float* sca   = ws + 96;            // 192
  float* ha    = ws + 288;           // 3145728 (later: m, then y2)
  float* hc    = ha + 3145728;       // 3145728 (later: kwA)
  float* x1g   = hc + 3145728;       // 3145728
  float* uf    = x1g + 3145728;      // 3145728
  float* att   = uf + 3145728;       // 1048576
  float* m     = ha;                              // m lifetime [k_gate, k_att2]
  unsigned int* y2 = (unsigned int*)ha;           // y2 lifetime [k_kba, k_proj]
  unsigned short* kwA = (unsigned short*)hc;      // hc dead after k_dw

  k_mean<<<96, 256, 0, stream>>>(x, xmean);
  k_sca <<<1, 256, 0, stream>>>(xmean, wsca, bsca, sca);
  k_pw1 <<<dim3(256, 4), 256, 0, stream>>>(x, w1a, b1a, w1c, b1c, ha, hc);
  k_dw  <<<6144, 256, 0, stream>>>(ha, hc, wdwa, bdwa, wdwc, bdwc, sca, x1g, uf);
  k_prep<<<384, 256, 0, stream>>>(kbw, kbb, kwA);
  k_gate<<<768, 256, 0, stream>>>(x, wc2a, bc2a, m);
  k_att2<<<dim3(256, 4), 256, 0, stream>>>(x, m, wc2b, bc2b, w211, b211, attg, att);
  k_kba <<<dim3(512, 6), 256, 0, stream>>>(uf, x1g, att, kwA, ga1, y2);
  k_proj<<<dim3(256, 4), 256, 0, stream>>>(y2, wproj, bproj, out);
}

// Round 11
// 109.307 us; speedup vs baseline: 1.1861x; 1.1861x over previous
//
#include <hip/hip_runtime.h>
#include <math.h>

#define HW 16384
#define Wd 128

typedef __attribute__((ext_vector_type(8))) short short8;
typedef __attribute__((ext_vector_type(4))) float f32x4;

__device__ __forceinline__ unsigned cvt_pk_bf16(float a, float b) {
  unsigned r;                                   // r = bf16(a) | bf16(b)<<16
  asm("v_cvt_pk_bf16_f32 %0, %1, %2" : "=v"(r) : "v"(a), "v"(b));
  return r;
}

__device__ __forceinline__ unsigned short bf16r(float f) {
  unsigned int u = __float_as_uint(f);
  unsigned int r = (u + 0x7FFFu + ((u >> 16) & 1u)) >> 16;   // RNE
  return (unsigned short)r;
}

// ---------------- K1: per (b,c) spatial mean ----------------
__global__ void k_mean(const float* __restrict__ x, float* __restrict__ xmean) {
  int bc = blockIdx.x;                       // 0..95  (b*48+c)
  const float* p = x + (size_t)bc * HW;
  float s = 0.f;
  for (int i = threadIdx.x; i < HW; i += 256) s += p[i];
  #pragma unroll
  for (int off = 32; off > 0; off >>= 1) s += __shfl_down(s, off, 64);
  __shared__ float wsum[4];
  int lane = threadIdx.x & 63, wv = threadIdx.x >> 6;
  if (lane == 0) wsum[wv] = s;
  __syncthreads();
  if (threadIdx.x == 0)
    xmean[bc] = (wsum[0] + wsum[1] + wsum[2] + wsum[3]) * (1.f / 16384.f);
}

__global__ void k_sca(const float* __restrict__ xmean, const float* __restrict__ w_sca,
                      const float* __restrict__ b_sca, float* __restrict__ sca) {
  int t = threadIdx.x;
  if (t < 192) {
    int b = t / 96, co = t % 96;
    float acc = b_sca[co];
    for (int ci = 0; ci < 48; ci++) acc += w_sca[co * 48 + ci] * xmean[b * 48 + ci];
    sca[t] = acc;
  }
}

// ---------------- K3: two 1x1 convs 48->96 (h_a, h_c) ----------------
// grid (512,4): 64 px per block; slot handles 6 out-channels
__global__ void k_pw1(const float* __restrict__ x,
                      const float* __restrict__ w1a, const float* __restrict__ b1a,
                      const float* __restrict__ w1c, const float* __restrict__ b1c,
                      float* __restrict__ ha, float* __restrict__ hc) {
  int lane = threadIdx.x & 63;
  int wv = __builtin_amdgcn_readfirstlane((int)(threadIdx.x >> 6));
  int slot = __builtin_amdgcn_readfirstlane((int)(blockIdx.y * 4 + wv));
  int p = blockIdx.x * 64 + lane;
  int b = p >> 14, sp = p & (HW - 1);
  const float* xb = x + (size_t)b * 48 * HW + sp;
  float xv[48];
  #pragma unroll
  for (int ci = 0; ci < 48; ci++) xv[ci] = xb[(size_t)ci * HW];
  float* hab = ha + (size_t)b * 96 * HW + sp;
  float* hcb = hc + (size_t)b * 96 * HW + sp;
  int c0 = slot * 6;
  for (int co = c0; co < c0 + 6; co++) {
    float aa = b1a[co], ac = b1c[co];
    const float* wa = w1a + co * 48;
    const float* wc = w1c + co * 48;
    #pragma unroll
    for (int ci = 0; ci < 48; ci++) { aa += wa[ci] * xv[ci]; ac += wc[ci] * xv[ci]; }
    hab[(size_t)co * HW] = aa;
    hcb[(size_t)co * HW] = ac;
  }
}

// ---------------- K4: depthwise 3x3; x1 path gets gelu*sca folded in ----------------
__global__ void k_dw(const float* __restrict__ ha, const float* __restrict__ hc,
                     const float* __restrict__ wdwa, const float* __restrict__ bdwa,
                     const float* __restrict__ wdwc, const float* __restrict__ bdwc,
                     const float* __restrict__ sca,
                     float* __restrict__ x1g, float* __restrict__ uf) {
  int idx = blockIdx.x * 256 + threadIdx.x;        // < B*96*HW
  int sp = idx & (HW - 1);
  int bc = idx >> 14;                              // b*96+ch
  int ch = bc % 96;
  int r = sp >> 7, c = sp & 127;
  const float* pa = ha + (size_t)bc * HW;
  const float* pc = hc + (size_t)bc * HW;
  float aa = bdwa[ch], ac = bdwc[ch];
  #pragma unroll
  for (int t9 = 0; t9 < 9; t9++) {
    int rr = r + t9 / 3 - 1, cc = c + t9 % 3 - 1;
    bool ok = ((unsigned)rr < 128u) && ((unsigned)cc < 128u);
    float va = ok ? pa[rr * Wd + cc] : 0.f;
    float vc = ok ? pc[rr * Wd + cc] : 0.f;
    aa += wdwa[ch * 9 + t9] * va;
    ac += wdwc[ch * 9 + t9] * vc;
  }
  float gl = aa * 0.5f * (1.f + erff(aa * 0.70710678118654752440f));
  x1g[idx] = gl * sca[bc];
  uf[idx] = ac;
}

// ---------------- K5a: gate m = t1*t2 (grouped 3x3 + SimpleGate) ----------------
__global__ void k_gate(const float* __restrict__ x, const float* __restrict__ wc2a,
                       const float* __restrict__ bc2a, float* __restrict__ m) {
  int idx = blockIdx.x * 256 + threadIdx.x;        // < B*12*HW = 393216
  int sp = idx & (HW - 1);
  int bi = idx >> 14;                              // b*12+i
  int i = bi % 12, b = bi / 12;
  int r = sp >> 7, c = sp & 127;
  const float* xb = x + (size_t)b * 48 * HW;
  float t[2];
  #pragma unroll
  for (int half = 0; half < 2; half++) {
    int o = i + half * 12;
    float acc = bc2a[o];
    #pragma unroll
    for (int ic = 0; ic < 2; ic++) {
      const float* xc = xb + (size_t)(2 * o + ic) * HW;
      const float* wo = wc2a + o * 18 + ic * 9;
      #pragma unroll
      for (int t9 = 0; t9 < 9; t9++) {
        int rr = r + t9 / 3 - 1, cc = c + t9 % 3 - 1;
        float v = (((unsigned)rr < 128u) && ((unsigned)cc < 128u)) ? xc[rr * Wd + cc] : 0.f;
        acc += wo[t9] * v;
      }
    }
    t[half] = acc;
  }
  m[idx] = t[0] * t[1];
}

// ---------------- K5b: att = 1x1(m)*gamma + 1x1(x) ----------------
// grid (512,4): slot (0..15) handles 2 att channels
__global__ void k_att2(const float* __restrict__ x, const float* __restrict__ m,
                       const float* __restrict__ wc2b, const float* __restrict__ bc2b,
                       const float* __restrict__ w211, const float* __restrict__ b211,
                       const float* __restrict__ attg, float* __restrict__ att) {
  int lane = threadIdx.x & 63;
  int wv = __builtin_amdgcn_readfirstlane((int)(threadIdx.x >> 6));
  int slot = __builtin_amdgcn_readfirstlane((int)(blockIdx.y * 4 + wv));
  int p = blockIdx.x * 64 + lane;
  int b = p >> 14, sp = p & (HW - 1);
  float mv[12];
  const float* mb = m + (size_t)b * 12 * HW + sp;
  #pragma unroll
  for (int i = 0; i < 12; i++) mv[i] = mb[(size_t)i * HW];
  float xv[48];
  const float* xb = x + (size_t)b * 48 * HW + sp;
  #pragma unroll
  for (int ci = 0; ci < 48; ci++) xv[ci] = xb[(size_t)ci * HW];
  float* ab = att + (size_t)b * 32 * HW + sp;
  int n0 = slot * 2;
  for (int n = n0; n < n0 + 2; n++) {
    float a1 = bc2b[n];
    #pragma unroll
    for (int i = 0; i < 12; i++) a1 += wc2b[n * 12 + i] * mv[i];
    float a2 = b211[n];
    #pragma unroll
    for (int ci = 0; ci < 48; ci++) a2 += w211[n * 48 + ci] * xv[ci];
    ab[(size_t)n * HW] = a1 * attg[n] + a2;
  }
}

// ---------------- K_prep: repack kbw+kbb -> bf16 A-tile [48][64][32] ----------------
// K-slot map (center-aligned; q = k>>3, j2 = k&7):
//   q0: j2<5 -> jj = j2        (ch0 taps 0-4; center jj=4 at j2=4)
//   q1: j2<5 -> jj = 9+j2      (ch1 taps 0-4; center jj=13 at j2=4)
//   q2: j2<4 -> jj = 5+j2      (ch0 taps 5-8)
//   q3: j2<4 -> jj = 14+j2     (ch1 taps 5-8); j2==4 -> bias
__global__ void k_prep(const float* __restrict__ kbw, const float* __restrict__ kbb,
                       unsigned short* __restrict__ kwA) {
  int e = blockIdx.x * 256 + threadIdx.x;          // < 48*64*32 = 98304
  int k = e & 31, nc = (e >> 5) & 63, g = e >> 11;
  int n = nc >> 1, i = nc & 1;
  int q = k >> 3, j2 = k & 7;
  float v = 0.f;
  int jj = -1;
  if (q == 0)      { if (j2 < 5) jj = j2; }
  else if (q == 1) { if (j2 < 5) jj = 9 + j2; }
  else if (q == 2) { if (j2 < 4) jj = 5 + j2; }
  else             { if (j2 < 4) jj = 14 + j2; else if (j2 == 4) v = kbb[n * 96 + 2 * g + i]; }
  if (jj >= 0) v = kbw[n * 1728 + g * 36 + i * 18 + jj];
  kwA[e] = bf16r(v);
}

// ---------------- K6: fused kba via MFMA ----------------
// grid (512,12) x 256. Wave wv owns px [wv*16,+16); block covers 4 groups gq*4..+3.
// kwA staged in LDS (16 KB); ALL loop-body global reads (20 taps, 8 x1g, 8 att)
// prefetched in the preamble -> loop body is pure LDS+MFMA+VALU + y2 stores.
// Output y2: packed bf16 channel-pairs [B][48][HW] (u32 = ch_even | ch_odd<<16).
__global__ __launch_bounds__(256) void k_kba(
    const float* __restrict__ uf, const float* __restrict__ x1g,
    const float* __restrict__ att, const unsigned short* __restrict__ kwA,
    const float* __restrict__ ga1, unsigned int* __restrict__ y2) {
  __shared__ __align__(16) short kwS[4 * 2048];    // 16 KB
  int tid = threadIdx.x;
  int lane = tid & 63;
  int wv = tid >> 6;
  int lo = lane & 15, hi = lane >> 4;
  int bid = blockIdx.x;                            // 0..511
  int b = bid >> 8;
  int sp = ((bid & 255) << 6) + wv * 16 + lo;      // this lane's pixel
  int r = sp >> 7, c = sp & 127;
  int g0 = blockIdx.y * 4;

  // stage this block's 4 groups of kwA into LDS (coalesced 16B copies)
  {
    const short8* src = (const short8*)(kwA + g0 * 2048);
    short8* dst = (short8*)kwS;
    #pragma unroll
    for (int i = 0; i < 4; i++) dst[tid + 256 * i] = src[tid + 256 * i];
  }

  const float* ufb  = uf  + (size_t)b * 96 * HW;
  const float* x1gb = x1g + (size_t)b * 96 * HW;
  const float* attb = att + (size_t)b * 32 * HW;
  unsigned int* y2b = y2 + (size_t)b * 48 * HW;

  // att[n][sp] for this lane's 8 n-slots: n = 8*mt + 2*hi + q
  float attv[8];
  #pragma unroll
  for (int mt = 0; mt < 4; mt++)
    #pragma unroll
    for (int q = 0; q < 2; q++)
      attv[mt * 2 + q] = attb[(size_t)(8 * mt + 2 * hi + q) * HW + sp];

  // tap descriptors for this lane's 5 K-slots (must match k_prep exactly;
  // the shared (hi,j2)->jj permutation cancels inside the MFMA)
  const float* pj[5];
  bool ok[5];
  float dv[5];
  #pragma unroll
  for (int j2 = 0; j2 < 5; j2++) {
    int jj = (hi == 0) ? j2 : (hi == 1) ? 9 + j2 : (hi == 2) ? 5 + j2 : 14 + j2;
    bool real = (hi < 2) || (j2 < 4);
    if (real) {
      int ch = jj / 9, tap = jj % 9;
      int rr = r + tap / 3 - 1, cc = c + tap % 3 - 1;
      bool inb = ((unsigned)rr < 128u) && ((unsigned)cc < 128u);
      ok[j2] = inb;
      dv[j2] = 0.f;
      pj[j2] = ufb + (size_t)(2 * g0 + ch) * HW + (inb ? rr * Wd + cc : 0);
    } else {
      ok[j2] = false;
      dv[j2] = (hi == 3) ? 1.f : 0.f;              // bias slot (q3, j2==4)
      pj[j2] = ufb;
    }
  }

  // prefetch ALL 4 groups' taps (20 loads) and the 8 x1g values
  float vT[4][5];
  #pragma unroll
  for (int gi = 0; gi < 4; gi++)
    #pragma unroll
    for (int j2 = 0; j2 < 5; j2++)
      vT[gi][j2] = ok[j2] ? pj[j2][(size_t)(2 * gi) * HW] : dv[j2];
  float x1v[8];                                    // channel 2*g0+k
  #pragma unroll
  for (int k = 0; k < 8; k++)
    x1v[k] = x1gb[(size_t)(2 * g0 + k) * HW + sp];

  __syncthreads();                                 // staging complete

  #pragma unroll
  for (int gp = 0; gp < 2; gp++) {
    int g = g0 + 2 * gp;
    float* va = vT[2 * gp];
    float* vb = vT[2 * gp + 1];
    // A-frags from LDS (conflict-free: lane byte addr = lo*64 + hi*16)
    const short* kgA = kwS + (2 * gp) * 2048;
    const short* kgB = kgA + 2048;
    short8 afrA[4], afrB[4];
    #pragma unroll
    for (int mt = 0; mt < 4; mt++) {
      afrA[mt] = *(const short8*)(kgA + (16 * mt + lo) * 32 + hi * 8);
      afrB[mt] = *(const short8*)(kgB + (16 * mt + lo) * 32 + hi * 8);
    }
    union { unsigned u[4]; short8 s; } bfA, bfB;
    bfA.u[0] = cvt_pk_bf16(va[0], va[1]);
    bfA.u[1] = cvt_pk_bf16(va[2], va[3]);
    bfA.u[2] = cvt_pk_bf16(va[4], 0.f);
    bfA.u[3] = 0u;
    bfB.u[0] = cvt_pk_bf16(vb[0], vb[1]);
    bfB.u[1] = cvt_pk_bf16(vb[2], vb[3]);
    bfB.u[2] = cvt_pk_bf16(vb[4], 0.f);
    bfB.u[3] = 0u;
    f32x4 accA[4], accB[4];
    f32x4 zero = {0.f, 0.f, 0.f, 0.f};
    #pragma unroll
    for (int mt = 0; mt < 4; mt++)
      accA[mt] = __builtin_amdgcn_mfma_f32_16x16x32_bf16(afrA[mt], bfA.s, zero, 0, 0, 0);
    #pragma unroll
    for (int mt = 0; mt < 4; mt++)
      accB[mt] = __builtin_amdgcn_mfma_f32_16x16x32_bf16(afrB[mt], bfB.s, zero, 0, 0, 0);
    // --- reduce over n (group A overlaps group B's MFMA latency) ---
    float sA0 = 0.f, sA1 = 0.f, sB0 = 0.f, sB1 = 0.f;
    #pragma unroll
    for (int mt = 0; mt < 4; mt++) {
      sA0 += attv[mt * 2 + 0] * accA[mt][0] + attv[mt * 2 + 1] * accA[mt][2];
      sA1 += attv[mt * 2 + 0] * accA[mt][1] + attv[mt * 2 + 1] * accA[mt][3];
    }
    sA0 += __shfl_xor(sA0, 16); sA0 += __shfl_xor(sA0, 32);
    sA1 += __shfl_xor(sA1, 16); sA1 += __shfl_xor(sA1, 32);
    float cenA = __shfl_xor(va[4], 16);
    #pragma unroll
    for (int mt = 0; mt < 4; mt++) {
      sB0 += attv[mt * 2 + 0] * accB[mt][0] + attv[mt * 2 + 1] * accB[mt][2];
      sB1 += attv[mt * 2 + 0] * accB[mt][1] + attv[mt * 2 + 1] * accB[mt][3];
    }
    sB0 += __shfl_xor(sB0, 16); sB0 += __shfl_xor(sB0, 32);
    sB1 += __shfl_xor(sB1, 16); sB1 += __shfl_xor(sB1, 32);
    float cenB = __shfl_xor(vb[4], 16);
    // --- epilogue: quarter 0 packs & stores both channels of both groups ---
    if (hi == 0) {
      int c0 = 2 * g;
      float xa0 = sA0 * ga1[c0]     + va[4];
      float xa1 = sA1 * ga1[c0 + 1] + cenA;
      float ya0 = x1v[4 * gp]     * xa0;
      float ya1 = x1v[4 * gp + 1] * xa1;
      y2b[(size_t)g * HW + sp] = cvt_pk_bf16(ya0, ya1);
      float xb0 = sB0 * ga1[c0 + 2] + vb[4];
      float xb1 = sB1 * ga1[c0 + 3] + cenB;
      float yb0 = x1v[4 * gp + 2] * xb0;
      float yb1 = x1v[4 * gp + 3] * xb1;
      y2b[(size_t)(g + 1) * HW + sp] = cvt_pk_bf16(yb0, yb1);
    }
  }
}

// ---------------- K7: project_out 96->48 from packed bf16 y2 ----------------
// grid (512,4): slot (0..15) handles 3 out-channels
__global__ void k_proj(const unsigned int* __restrict__ y2, const float* __restrict__ wproj,
                       const float* __restrict__ bproj, float* __restrict__ out) {
  int lane = threadIdx.x & 63;
  int wv = __builtin_amdgcn_readfirstlane((int)(threadIdx.x >> 6));
  int slot = __builtin_amdgcn_readfirstlane((int)(blockIdx.y * 4 + wv));
  int p = blockIdx.x * 64 + lane;
  int b = p >> 14, sp = p & (HW - 1);
  const unsigned int* yb = y2 + (size_t)b * 48 * HW + sp;
  float yv[96];
  #pragma unroll
  for (int i = 0; i < 48; i++) {
    unsigned u = yb[(size_t)i * HW];
    yv[2 * i]     = __uint_as_float(u << 16);
    yv[2 * i + 1] = __uint_as_float(u & 0xffff0000u);
  }
  float* ob = out + (size_t)b * 48 * HW + sp;
  int co0 = slot * 3;
  for (int co = co0; co < co0 + 3; co++) {
    float acc = bproj[co];
    const float* w = wproj + co * 96;
    #pragma unroll
    for (int ch = 0; ch < 96; ch++) acc += w[ch] * yv[ch];
    ob[(size_t)co * HW] = acc;
  }
}

extern "C" void kernel_launch(void* const* d_in, const int* in_sizes, int n_in,
                              void* d_out, int out_size, void* d_ws, size_t ws_size,
                              hipStream_t stream) {
  const float* x    = (const float*)d_in[0];
  const float* w1a  = (const float*)d_in[1];
  const float* b1a  = (const float*)d_in[2];
  const float* wdwa = (const float*)d_in[3];
  const float* bdwa = (const float*)d_in[4];
  const float* w1c  = (const float*)d_in[5];
  const float* b1c  = (const float*)d_in[6];
  const float* wdwc = (const float*)d_in[7];
  const float* bdwc = (const float*)d_in[8];
  const float* wsca = (const float*)d_in[9];
  const float* bsca = (const float*)d_in[10];
  const float* wc2a = (const float*)d_in[11];
  const float* bc2a = (const float*)d_in[12];
  const float* wc2b = (const float*)d_in[13];
  const float* bc2b = (const float*)d_in[14];
  const float* w211 = (const float*)d_in[15];
  const float* b211 = (const float*)d_in[16];
  const float* wproj= (const float*)d_in[17];
  const float* bproj= (const float*)d_in[18];
  const float* kbw  = (const float*)d_in[19];
  const float* kbb  = (const float*)d_in[20];
  const float* attg = (const float*)d_in[21];
  const float* ga1  = (const float*)d_in[22];
  float* out = (float*)d_out;

  float* ws    = (float*)d_ws;
  float* xmean = ws;                 // 96
  float* sca   = ws + 96;            // 192
  float* ha    = ws + 288;           // 3145728 (later: m, then y2)
  float* hc    = ha + 3145728;       // 3145728 (later: kwA)
  float* x1g   = hc + 3145728;       // 3145728
  float* uf    = x1g + 3145728;      // 3145728
  float* att   = uf + 3145728;       // 1048576
  float* m     = ha;                              // m lifetime [k_gate, k_att2]
  unsigned int* y2 = (unsigned int*)ha;           // y2 lifetime [k_kba, k_proj]
  unsigned short* kwA = (unsigned short*)hc;      // hc dead after k_dw

  k_mean<<<96, 256, 0, stream>>>(x, xmean);
  k_sca <<<1, 256, 0, stream>>>(xmean, wsca, bsca, sca);
  k_pw1 <<<dim3(512, 4), 256, 0, stream>>>(x, w1a, b1a, w1c, b1c, ha, hc);
  k_dw  <<<12288, 256, 0, stream>>>(ha, hc, wdwa, bdwa, wdwc, bdwc, sca, x1g, uf);
  k_prep<<<384, 256, 0, stream>>>(kbw, kbb, kwA);
  k_gate<<<1536, 256, 0, stream>>>(x, wc2a, bc2a, m);
  k_att2<<<dim3(512, 4), 256, 0, stream>>>(x, m, wc2b, bc2b, w211, b211, attg, att);
  k_kba <<<dim3(512, 12), 256, 0, stream>>>(uf, x1g, att, kwA, ga1, y2);
  k_proj<<<dim3(512, 4), 256, 0, stream>>>(y2, wproj, bproj, out);
}

// Round 12
// 108.160 us; speedup vs baseline: 1.1987x; 1.0106x over previous
//
#include <hip/hip_runtime.h>
#include <math.h>

#define HW 16384
#define Wd 128

typedef __attribute__((ext_vector_type(8))) short short8;
typedef __attribute__((ext_vector_type(4))) float f32x4;

__device__ __forceinline__ unsigned cvt_pk_bf16(float a, float b) {
  unsigned r;                                   // r = bf16(a) | bf16(b)<<16
  asm("v_cvt_pk_bf16_f32 %0, %1, %2" : "=v"(r) : "v"(a), "v"(b));
  return r;
}

__device__ __forceinline__ unsigned short bf16r(float f) {
  unsigned int u = __float_as_uint(f);
  unsigned int r = (u + 0x7FFFu + ((u >> 16) & 1u)) >> 16;   // RNE
  return (unsigned short)r;
}

// ---------------- K1: per (b,c) spatial mean ----------------
__global__ void k_mean(const float* __restrict__ x, float* __restrict__ xmean) {
  int bc = blockIdx.x;                       // 0..95  (b*48+c)
  const float* p = x + (size_t)bc * HW;
  float s = 0.f;
  for (int i = threadIdx.x; i < HW; i += 256) s += p[i];
  #pragma unroll
  for (int off = 32; off > 0; off >>= 1) s += __shfl_down(s, off, 64);
  __shared__ float wsum[4];
  int lane = threadIdx.x & 63, wv = threadIdx.x >> 6;
  if (lane == 0) wsum[wv] = s;
  __syncthreads();
  if (threadIdx.x == 0)
    xmean[bc] = (wsum[0] + wsum[1] + wsum[2] + wsum[3]) * (1.f / 16384.f);
}

__global__ void k_sca(const float* __restrict__ xmean, const float* __restrict__ w_sca,
                      const float* __restrict__ b_sca, float* __restrict__ sca) {
  int t = threadIdx.x;
  if (t < 192) {
    int b = t / 96, co = t % 96;
    float acc = b_sca[co];
    for (int ci = 0; ci < 48; ci++) acc += w_sca[co * 48 + ci] * xmean[b * 48 + ci];
    sca[t] = acc;
  }
}

// ---------------- K3: two 1x1 convs 48->96 + w211 1x1 (a2 of att) ----------------
// grid (512,4): 64 px per block; slot handles 6 h-channels + 2 att channels
__global__ void k_pw1(const float* __restrict__ x,
                      const float* __restrict__ w1a, const float* __restrict__ b1a,
                      const float* __restrict__ w1c, const float* __restrict__ b1c,
                      const float* __restrict__ w211, const float* __restrict__ b211,
                      float* __restrict__ ha, float* __restrict__ hc,
                      float* __restrict__ att) {
  int lane = threadIdx.x & 63;
  int wv = __builtin_amdgcn_readfirstlane((int)(threadIdx.x >> 6));
  int slot = __builtin_amdgcn_readfirstlane((int)(blockIdx.y * 4 + wv));
  int p = blockIdx.x * 64 + lane;
  int b = p >> 14, sp = p & (HW - 1);
  const float* xb = x + (size_t)b * 48 * HW + sp;
  float xv[48];
  #pragma unroll
  for (int ci = 0; ci < 48; ci++) xv[ci] = xb[(size_t)ci * HW];
  float* hab = ha + (size_t)b * 96 * HW + sp;
  float* hcb = hc + (size_t)b * 96 * HW + sp;
  int c0 = slot * 6;
  for (int co = c0; co < c0 + 6; co++) {
    float aa = b1a[co], ac = b1c[co];
    const float* wa = w1a + co * 48;
    const float* wc = w1c + co * 48;
    #pragma unroll
    for (int ci = 0; ci < 48; ci++) { aa += wa[ci] * xv[ci]; ac += wc[ci] * xv[ci]; }
    hab[(size_t)co * HW] = aa;
    hcb[(size_t)co * HW] = ac;
  }
  // a2 part of att: att[n] = b211[n] + w211[n]·x  (a1*gamma added in k_att2)
  float* ab = att + (size_t)b * 32 * HW + sp;
  int n0 = slot * 2;
  for (int n = n0; n < n0 + 2; n++) {
    float a2 = b211[n];
    const float* w2 = w211 + n * 48;
    #pragma unroll
    for (int ci = 0; ci < 48; ci++) a2 += w2[ci] * xv[ci];
    ab[(size_t)n * HW] = a2;
  }
}

// ---------------- K4: depthwise 3x3; x1 path gets gelu*sca folded in ----------------
__global__ void k_dw(const float* __restrict__ ha, const float* __restrict__ hc,
                     const float* __restrict__ wdwa, const float* __restrict__ bdwa,
                     const float* __restrict__ wdwc, const float* __restrict__ bdwc,
                     const float* __restrict__ sca,
                     float* __restrict__ x1g, float* __restrict__ uf) {
  int idx = blockIdx.x * 256 + threadIdx.x;        // < B*96*HW
  int sp = idx & (HW - 1);
  int bc = idx >> 14;                              // b*96+ch
  int ch = bc % 96;
  int r = sp >> 7, c = sp & 127;
  const float* pa = ha + (size_t)bc * HW;
  const float* pc = hc + (size_t)bc * HW;
  float aa = bdwa[ch], ac = bdwc[ch];
  #pragma unroll
  for (int t9 = 0; t9 < 9; t9++) {
    int rr = r + t9 / 3 - 1, cc = c + t9 % 3 - 1;
    bool ok = ((unsigned)rr < 128u) && ((unsigned)cc < 128u);
    float va = ok ? pa[rr * Wd + cc] : 0.f;
    float vc = ok ? pc[rr * Wd + cc] : 0.f;
    aa += wdwa[ch * 9 + t9] * va;
    ac += wdwc[ch * 9 + t9] * vc;
  }
  float gl = aa * 0.5f * (1.f + erff(aa * 0.70710678118654752440f));
  x1g[idx] = gl * sca[bc];
  uf[idx] = ac;
}

// ---------------- K5a: gate m = t1*t2 (grouped 3x3 + SimpleGate) ----------------
__global__ void k_gate(const float* __restrict__ x, const float* __restrict__ wc2a,
                       const float* __restrict__ bc2a, float* __restrict__ m) {
  int idx = blockIdx.x * 256 + threadIdx.x;        // < B*12*HW = 393216
  int sp = idx & (HW - 1);
  int bi = idx >> 14;                              // b*12+i
  int i = bi % 12, b = bi / 12;
  int r = sp >> 7, c = sp & 127;
  const float* xb = x + (size_t)b * 48 * HW;
  float t[2];
  #pragma unroll
  for (int half = 0; half < 2; half++) {
    int o = i + half * 12;
    float acc = bc2a[o];
    #pragma unroll
    for (int ic = 0; ic < 2; ic++) {
      const float* xc = xb + (size_t)(2 * o + ic) * HW;
      const float* wo = wc2a + o * 18 + ic * 9;
      #pragma unroll
      for (int t9 = 0; t9 < 9; t9++) {
        int rr = r + t9 / 3 - 1, cc = c + t9 % 3 - 1;
        float v = (((unsigned)rr < 128u) && ((unsigned)cc < 128u)) ? xc[rr * Wd + cc] : 0.f;
        acc += wo[t9] * v;
      }
    }
    t[half] = acc;
  }
  m[idx] = t[0] * t[1];
}

// ---------------- K5b: att += 1x1(m)*gamma, IN PLACE (a2 already there) ----------
// grid (512,2): slot (0..7) handles 4 att channels; 1:1 thread<->addr, no race
__global__ void k_att2(const float* __restrict__ m,
                       const float* __restrict__ wc2b, const float* __restrict__ bc2b,
                       const float* __restrict__ attg, float* __restrict__ att) {
  int lane = threadIdx.x & 63;
  int wv = __builtin_amdgcn_readfirstlane((int)(threadIdx.x >> 6));
  int slot = __builtin_amdgcn_readfirstlane((int)(blockIdx.y * 4 + wv));
  int p = blockIdx.x * 64 + lane;
  int b = p >> 14, sp = p & (HW - 1);
  float mv[12];
  const float* mb = m + (size_t)b * 12 * HW + sp;
  #pragma unroll
  for (int i = 0; i < 12; i++) mv[i] = mb[(size_t)i * HW];
  float* ab = att + (size_t)b * 32 * HW + sp;
  int n0 = slot * 4;
  for (int n = n0; n < n0 + 4; n++) {
    float a1 = bc2b[n];
    #pragma unroll
    for (int i = 0; i < 12; i++) a1 += wc2b[n * 12 + i] * mv[i];
    float* ap = ab + (size_t)n * HW;
    *ap = a1 * attg[n] + *ap;
  }
}

// ---------------- K_prep: repack kbw+kbb -> bf16 A-tile [48][64][32] ----------------
// K-slot map (center-aligned; q = k>>3, j2 = k&7):
//   q0: j2<5 -> jj = j2        (ch0 taps 0-4; center jj=4 at j2=4)
//   q1: j2<5 -> jj = 9+j2      (ch1 taps 0-4; center jj=13 at j2=4)
//   q2: j2<4 -> jj = 5+j2      (ch0 taps 5-8)
//   q3: j2<4 -> jj = 14+j2     (ch1 taps 5-8); j2==4 -> bias
__global__ void k_prep(const float* __restrict__ kbw, const float* __restrict__ kbb,
                       unsigned short* __restrict__ kwA) {
  int e = blockIdx.x * 256 + threadIdx.x;          // < 48*64*32 = 98304
  int k = e & 31, nc = (e >> 5) & 63, g = e >> 11;
  int n = nc >> 1, i = nc & 1;
  int q = k >> 3, j2 = k & 7;
  float v = 0.f;
  int jj = -1;
  if (q == 0)      { if (j2 < 5) jj = j2; }
  else if (q == 1) { if (j2 < 5) jj = 9 + j2; }
  else if (q == 2) { if (j2 < 4) jj = 5 + j2; }
  else             { if (j2 < 4) jj = 14 + j2; else if (j2 == 4) v = kbb[n * 96 + 2 * g + i]; }
  if (jj >= 0) v = kbw[n * 1728 + g * 36 + i * 18 + jj];
  kwA[e] = bf16r(v);
}

// ---------------- K_prepw: wproj -> bf16 hi + bf16 lo residual ----------------
__global__ void k_prepw(const float* __restrict__ wproj, unsigned short* __restrict__ wp) {
  int e = blockIdx.x * 256 + threadIdx.x;          // < 4608 (48*96)
  if (e < 4608) {
    float w = wproj[e];
    unsigned short h = bf16r(w);
    wp[e] = h;
    float hif = __uint_as_float((unsigned)h << 16);
    wp[4608 + e] = bf16r(w - hif);
  }
}

// ---------------- K6: fused kba via MFMA (unchanged from r11) ----------------
__global__ __launch_bounds__(256) void k_kba(
    const float* __restrict__ uf, const float* __restrict__ x1g,
    const float* __restrict__ att, const unsigned short* __restrict__ kwA,
    const float* __restrict__ ga1, unsigned int* __restrict__ y2) {
  __shared__ __align__(16) short kwS[4 * 2048];    // 16 KB
  int tid = threadIdx.x;
  int lane = tid & 63;
  int wv = tid >> 6;
  int lo = lane & 15, hi = lane >> 4;
  int bid = blockIdx.x;                            // 0..511
  int b = bid >> 8;
  int sp = ((bid & 255) << 6) + wv * 16 + lo;      // this lane's pixel
  int r = sp >> 7, c = sp & 127;
  int g0 = blockIdx.y * 4;

  {
    const short8* src = (const short8*)(kwA + g0 * 2048);
    short8* dst = (short8*)kwS;
    #pragma unroll
    for (int i = 0; i < 4; i++) dst[tid + 256 * i] = src[tid + 256 * i];
  }

  const float* ufb  = uf  + (size_t)b * 96 * HW;
  const float* x1gb = x1g + (size_t)b * 96 * HW;
  const float* attb = att + (size_t)b * 32 * HW;
  unsigned int* y2b = y2 + (size_t)b * 48 * HW;

  float attv[8];
  #pragma unroll
  for (int mt = 0; mt < 4; mt++)
    #pragma unroll
    for (int q = 0; q < 2; q++)
      attv[mt * 2 + q] = attb[(size_t)(8 * mt + 2 * hi + q) * HW + sp];

  const float* pj[5];
  bool ok[5];
  float dv[5];
  #pragma unroll
  for (int j2 = 0; j2 < 5; j2++) {
    int jj = (hi == 0) ? j2 : (hi == 1) ? 9 + j2 : (hi == 2) ? 5 + j2 : 14 + j2;
    bool real = (hi < 2) || (j2 < 4);
    if (real) {
      int ch = jj / 9, tap = jj % 9;
      int rr = r + tap / 3 - 1, cc = c + tap % 3 - 1;
      bool inb = ((unsigned)rr < 128u) && ((unsigned)cc < 128u);
      ok[j2] = inb;
      dv[j2] = 0.f;
      pj[j2] = ufb + (size_t)(2 * g0 + ch) * HW + (inb ? rr * Wd + cc : 0);
    } else {
      ok[j2] = false;
      dv[j2] = (hi == 3) ? 1.f : 0.f;              // bias slot (q3, j2==4)
      pj[j2] = ufb;
    }
  }

  float vT[4][5];
  #pragma unroll
  for (int gi = 0; gi < 4; gi++)
    #pragma unroll
    for (int j2 = 0; j2 < 5; j2++)
      vT[gi][j2] = ok[j2] ? pj[j2][(size_t)(2 * gi) * HW] : dv[j2];
  float x1v[8];
  #pragma unroll
  for (int k = 0; k < 8; k++)
    x1v[k] = x1gb[(size_t)(2 * g0 + k) * HW + sp];

  __syncthreads();

  #pragma unroll
  for (int gp = 0; gp < 2; gp++) {
    int g = g0 + 2 * gp;
    float* va = vT[2 * gp];
    float* vb = vT[2 * gp + 1];
    const short* kgA = kwS + (2 * gp) * 2048;
    const short* kgB = kgA + 2048;
    short8 afrA[4], afrB[4];
    #pragma unroll
    for (int mt = 0; mt < 4; mt++) {
      afrA[mt] = *(const short8*)(kgA + (16 * mt + lo) * 32 + hi * 8);
      afrB[mt] = *(const short8*)(kgB + (16 * mt + lo) * 32 + hi * 8);
    }
    union { unsigned u[4]; short8 s; } bfA, bfB;
    bfA.u[0] = cvt_pk_bf16(va[0], va[1]);
    bfA.u[1] = cvt_pk_bf16(va[2], va[3]);
    bfA.u[2] = cvt_pk_bf16(va[4], 0.f);
    bfA.u[3] = 0u;
    bfB.u[0] = cvt_pk_bf16(vb[0], vb[1]);
    bfB.u[1] = cvt_pk_bf16(vb[2], vb[3]);
    bfB.u[2] = cvt_pk_bf16(vb[4], 0.f);
    bfB.u[3] = 0u;
    f32x4 accA[4], accB[4];
    f32x4 zero = {0.f, 0.f, 0.f, 0.f};
    #pragma unroll
    for (int mt = 0; mt < 4; mt++)
      accA[mt] = __builtin_amdgcn_mfma_f32_16x16x32_bf16(afrA[mt], bfA.s, zero, 0, 0, 0);
    #pragma unroll
    for (int mt = 0; mt < 4; mt++)
      accB[mt] = __builtin_amdgcn_mfma_f32_16x16x32_bf16(afrB[mt], bfB.s, zero, 0, 0, 0);
    float sA0 = 0.f, sA1 = 0.f, sB0 = 0.f, sB1 = 0.f;
    #pragma unroll
    for (int mt = 0; mt < 4; mt++) {
      sA0 += attv[mt * 2 + 0] * accA[mt][0] + attv[mt * 2 + 1] * accA[mt][2];
      sA1 += attv[mt * 2 + 0] * accA[mt][1] + attv[mt * 2 + 1] * accA[mt][3];
    }
    sA0 += __shfl_xor(sA0, 16); sA0 += __shfl_xor(sA0, 32);
    sA1 += __shfl_xor(sA1, 16); sA1 += __shfl_xor(sA1, 32);
    float cenA = __shfl_xor(va[4], 16);
    #pragma unroll
    for (int mt = 0; mt < 4; mt++) {
      sB0 += attv[mt * 2 + 0] * accB[mt][0] + attv[mt * 2 + 1] * accB[mt][2];
      sB1 += attv[mt * 2 + 0] * accB[mt][1] + attv[mt * 2 + 1] * accB[mt][3];
    }
    sB0 += __shfl_xor(sB0, 16); sB0 += __shfl_xor(sB0, 32);
    sB1 += __shfl_xor(sB1, 16); sB1 += __shfl_xor(sB1, 32);
    float cenB = __shfl_xor(vb[4], 16);
    if (hi == 0) {
      int c0 = 2 * g;
      float xa0 = sA0 * ga1[c0]     + va[4];
      float xa1 = sA1 * ga1[c0 + 1] + cenA;
      float ya0 = x1v[4 * gp]     * xa0;
      float ya1 = x1v[4 * gp + 1] * xa1;
      y2b[(size_t)g * HW + sp] = cvt_pk_bf16(ya0, ya1);
      float xb0 = sB0 * ga1[c0 + 2] + vb[4];
      float xb1 = sB1 * ga1[c0 + 3] + cenB;
      float yb0 = x1v[4 * gp + 2] * xb0;
      float yb1 = x1v[4 * gp + 3] * xb1;
      y2b[(size_t)(g + 1) * HW + sp] = cvt_pk_bf16(yb0, yb1);
    }
  }
}

// ---------------- K7: project_out 96->48 via MFMA (W = bf16 hi + bf16 lo) -------
// grid 512 x 256. Wave handles 16 px, all 48 out-channels (3 row-tiles).
// B-frag: y2 packed pairs are exactly the (hi*8+j) k-order. Bias via C-in.
__global__ void k_proj(const unsigned int* __restrict__ y2, const unsigned short* __restrict__ wp,
                       const float* __restrict__ bproj, float* __restrict__ out) {
  int tid = threadIdx.x;
  int lane = tid & 63;
  int wv = tid >> 6;
  int lo = lane & 15, hi = lane >> 4;
  int p0 = blockIdx.x * 64 + wv * 16;
  int b = p0 >> 14;
  int sp = (p0 & (HW - 1)) + lo;
  const unsigned int* yb = y2 + (size_t)b * 48 * HW + sp;
  // B-frags for 3 k-steps: u[q] = y2[ch-pair ks*16 + hi*4 + q][px]
  union { unsigned u[4]; short8 s; } bf[3];
  #pragma unroll
  for (int ks = 0; ks < 3; ks++)
    #pragma unroll
    for (int q = 0; q < 4; q++)
      bf[ks].u[q] = yb[(size_t)(ks * 16 + hi * 4 + q) * HW];
  // acc init = bias (C/D row = 16t + 4hi + r)
  f32x4 acc[3];
  #pragma unroll
  for (int t = 0; t < 3; t++)
    #pragma unroll
    for (int r = 0; r < 4; r++)
      acc[t][r] = bproj[16 * t + 4 * hi + r];
  #pragma unroll
  for (int t = 0; t < 3; t++) {
    #pragma unroll
    for (int ks = 0; ks < 3; ks++) {
      short8 ah = *(const short8*)(wp + (16 * t + lo) * 96 + ks * 32 + hi * 8);
      acc[t] = __builtin_amdgcn_mfma_f32_16x16x32_bf16(ah, bf[ks].s, acc[t], 0, 0, 0);
      short8 al = *(const short8*)(wp + 4608 + (16 * t + lo) * 96 + ks * 32 + hi * 8);
      acc[t] = __builtin_amdgcn_mfma_f32_16x16x32_bf16(al, bf[ks].s, acc[t], 0, 0, 0);
    }
  }
  float* ob = out + (size_t)b * 48 * HW + sp;
  #pragma unroll
  for (int t = 0; t < 3; t++)
    #pragma unroll
    for (int r = 0; r < 4; r++)
      ob[(size_t)(16 * t + 4 * hi + r) * HW] = acc[t][r];
}

extern "C" void kernel_launch(void* const* d_in, const int* in_sizes, int n_in,
                              void* d_out, int out_size, void* d_ws, size_t ws_size,
                              hipStream_t stream) {
  const float* x    = (const float*)d_in[0];
  const float* w1a  = (const float*)d_in[1];
  const float* b1a  = (const float*)d_in[2];
  const float* wdwa = (const float*)d_in[3];
  const float* bdwa = (const float*)d_in[4];
  const float* w1c  = (const float*)d_in[5];
  const float* b1c  = (const float*)d_in[6];
  const float* wdwc = (const float*)d_in[7];
  const float* bdwc = (const float*)d_in[8];
  const float* wsca = (const float*)d_in[9];
  const float* bsca = (const float*)d_in[10];
  const float* wc2a = (const float*)d_in[11];
  const float* bc2a = (const float*)d_in[12];
  const float* wc2b = (const float*)d_in[13];
  const float* bc2b = (const float*)d_in[14];
  const float* w211 = (const float*)d_in[15];
  const float* b211 = (const float*)d_in[16];
  const float* wproj= (const float*)d_in[17];
  const float* bproj= (const float*)d_in[18];
  const float* kbw  = (const float*)d_in[19];
  const float* kbb  = (const float*)d_in[20];
  const float* attg = (const float*)d_in[21];
  const float* ga1  = (const float*)d_in[22];
  float* out = (float*)d_out;

  float* ws    = (float*)d_ws;
  float* xmean = ws;                 // 96
  float* sca   = ws + 96;            // 192
  float* ha    = ws + 288;           // 3145728 (later: m, then y2)
  float* hc    = ha + 3145728;       // 3145728 (later: kwA + wp)
  float* x1g   = hc + 3145728;       // 3145728
  float* uf    = x1g + 3145728;      // 3145728
  float* att   = uf + 3145728;       // 1048576
  float* m     = ha;                              // m lifetime [k_gate, k_att2]
  unsigned int* y2 = (unsigned int*)ha;           // y2 lifetime [k_kba, k_proj]
  unsigned short* kwA = (unsigned short*)hc;      // hc dead after k_dw
  unsigned short* wp  = kwA + 98304;              // wproj hi/lo bf16 (9216 u16)

  k_mean<<<96, 256, 0, stream>>>(x, xmean);
  k_sca <<<1, 256, 0, stream>>>(xmean, wsca, bsca, sca);
  k_pw1 <<<dim3(512, 4), 256, 0, stream>>>(x, w1a, b1a, w1c, b1c, w211, b211, ha, hc, att);
  k_dw  <<<12288, 256, 0, stream>>>(ha, hc, wdwa, bdwa, wdwc, bdwc, sca, x1g, uf);
  k_prep<<<384, 256, 0, stream>>>(kbw, kbb, kwA);
  k_prepw<<<18, 256, 0, stream>>>(wproj, wp);
  k_gate<<<1536, 256, 0, stream>>>(x, wc2a, bc2a, m);
  k_att2<<<dim3(512, 2), 256, 0, stream>>>(m, wc2b, bc2b, attg, att);
  k_kba <<<dim3(512, 12), 256, 0, stream>>>(uf, x1g, att, kwA, ga1, y2);
  k_proj<<<512, 256, 0, stream>>>(y2, wp, bproj, out);
}